// Round 4
// baseline (1725.541 us; speedup 1.0000x reference)
//
#include <hip/hip_runtime.h>
#include <math.h>

#define BB 8
#define NN 2048
#define DD 128
#define HH 128

typedef float f4 __attribute__((ext_vector_type(4)));

// ---------- fast math helpers ----------
__device__ __forceinline__ float fast_rcp(float x) { return __builtin_amdgcn_rcpf(x); }
__device__ __forceinline__ float sigmoidf_(float x) {
    x = fminf(fmaxf(x, -30.f), 30.f);
    return fast_rcp(1.f + __expf(-x));
}
__device__ __forceinline__ float tanhf_(float x) {
    x = fminf(fmaxf(x, -15.f), 15.f);
    float e = __expf(-2.f * x);
    return (1.f - e) * fast_rcp(1.f + e);
}

// DPP quad reduction: sum across the 4 lanes of each aligned quad (pure VALU).
__device__ __forceinline__ float quad_sum(float v) {
    int a = __builtin_amdgcn_update_dpp(0, __float_as_int(v), 0xB1, 0xF, 0xF, true);  // xor 1
    v += __int_as_float(a);
    int b = __builtin_amdgcn_update_dpp(0, __float_as_int(v), 0x4E, 0xF, 0xF, true);  // xor 2
    v += __int_as_float(b);
    return v;
}

// ---------------- Kernel 1: graph aggregation ----------------
#define TI 32
#define TJ 64

__global__ __launch_bounds__(256) void k_agg(const float* __restrict__ x,
                                             const int* __restrict__ adj,
                                             float* __restrict__ xa) {
    __shared__ __align__(16) float xs[TJ][132];
    __shared__ __align__(16) float as[TI][68];
    const int b = blockIdx.y;
    const int i0 = blockIdx.x * TI;
    const int tid = threadIdx.x;
    const int ig = tid >> 5;
    const int dg = tid & 31;
    const float* xb = x + (size_t)b * NN * DD;
    const int* ab = adj + (size_t)b * NN * NN;

    float acc[4][4];
    float deg[4];
#pragma unroll
    for (int i = 0; i < 4; ++i) {
        deg[i] = 0.f;
#pragma unroll
        for (int d = 0; d < 4; ++d) acc[i][d] = 0.f;
    }

    for (int j0 = 0; j0 < NN; j0 += TJ) {
#pragma unroll
        for (int k = 0; k < 8; ++k) {
            int idx = tid + k * 256;
            int row = idx >> 5, c4 = idx & 31;
            float4 v = *(const float4*)(xb + (size_t)(j0 + row) * DD + c4 * 4);
            *(float4*)(&xs[row][c4 * 4]) = v;
        }
#pragma unroll
        for (int k = 0; k < 2; ++k) {
            int idx = tid + k * 256;
            int row = idx >> 4, c4 = idx & 15;
            int4 v = *(const int4*)(ab + (size_t)(i0 + row) * NN + j0 + c4 * 4);
            float4 f;
            f.x = v.x > 0 ? 1.f : 0.f;
            f.y = v.y > 0 ? 1.f : 0.f;
            f.z = v.z > 0 ? 1.f : 0.f;
            f.w = v.w > 0 ? 1.f : 0.f;
            *(float4*)(&as[row][c4 * 4]) = f;
        }
        __syncthreads();
#pragma unroll 4
        for (int jq = 0; jq < TJ; jq += 4) {
            float4 av[4], xv[4];
#pragma unroll
            for (int i = 0; i < 4; ++i) av[i] = *(const float4*)(&as[ig * 4 + i][jq]);
#pragma unroll
            for (int jj = 0; jj < 4; ++jj) xv[jj] = *(const float4*)(&xs[jq + jj][dg * 4]);
#pragma unroll
            for (int i = 0; i < 4; ++i) {
                const float* ap = (const float*)&av[i];
#pragma unroll
                for (int jj = 0; jj < 4; ++jj) {
                    float a = ap[jj];
                    const float* xp4 = (const float*)&xv[jj];
                    deg[i] += a;
                    acc[i][0] = fmaf(a, xp4[0], acc[i][0]);
                    acc[i][1] = fmaf(a, xp4[1], acc[i][1]);
                    acc[i][2] = fmaf(a, xp4[2], acc[i][2]);
                    acc[i][3] = fmaf(a, xp4[3], acc[i][3]);
                }
            }
        }
        __syncthreads();
    }
#pragma unroll
    for (int i = 0; i < 4; ++i) {
        int gi = i0 + ig * 4 + i;
        float r = fast_rcp(1.f + deg[i]);
        float4 xv = *(const float4*)(xb + (size_t)gi * DD + dg * 4);
        float4 o;
        o.x = (xv.x + acc[i][0]) * r;
        o.y = (xv.y + acc[i][1]) * r;
        o.z = (xv.z + acc[i][2]) * r;
        o.w = (xv.w + acc[i][3]) * r;
        *(float4*)(xa + ((size_t)b * NN + gi) * DD + dg * 4) = o;
    }
}

// ---------------- Kernel 2: input projection (both dirs) ----------------
// Writes xp pre-permuted for k_lstm: gate (unit u, type j) -> slot 4*u+j.
// Backward dir also pre-reversed in time.
#define MT 64
#define GT 32

__global__ __launch_bounds__(256) void k_proj(const float* __restrict__ xa,
                                              const float* __restrict__ wif,
                                              const float* __restrict__ wib,
                                              const float* __restrict__ bif,
                                              const float* __restrict__ bhf,
                                              const float* __restrict__ bib,
                                              const float* __restrict__ bhb,
                                              float* __restrict__ xpf,
                                              float* __restrict__ xpb) {
    __shared__ __align__(16) float xs[MT][132];
    __shared__ __align__(16) float wl[GT][132];
    const int r0 = blockIdx.x * MT;
    const int g0 = blockIdx.y * GT;
    const int tid = threadIdx.x;
#pragma unroll
    for (int k = 0; k < 8; ++k) {
        int idx = tid + k * 256;
        int row = idx >> 5, c4 = idx & 31;
        int r = r0 + row;
        int t = r >> 3, bb = r & 7;
        float4 v = *(const float4*)(xa + ((size_t)bb * NN + t) * DD + c4 * 4);
        *(float4*)(&xs[row][c4 * 4]) = v;
    }
#pragma unroll
    for (int k = 0; k < 4; ++k) {
        int idx = tid + k * 256;
        int row = idx >> 5, c4 = idx & 31;
        int g = g0 + row;
        const float* wsrc = (g < 512) ? (wif + (size_t)g * DD) : (wib + (size_t)(g - 512) * DD);
        *(float4*)(&wl[row][c4 * 4]) = *(const float4*)(wsrc + c4 * 4);
    }
    __syncthreads();
    const int mg = tid >> 4;
    const int gg = tid & 15;
    float acc[4][2];
#pragma unroll
    for (int i = 0; i < 4; ++i) { acc[i][0] = 0.f; acc[i][1] = 0.f; }
#pragma unroll 8
    for (int d4 = 0; d4 < 32; ++d4) {
        float4 xv[4], wv[2];
#pragma unroll
        for (int i = 0; i < 4; ++i) xv[i] = *(const float4*)(&xs[mg * 4 + i][d4 * 4]);
        wv[0] = *(const float4*)(&wl[gg * 2 + 0][d4 * 4]);
        wv[1] = *(const float4*)(&wl[gg * 2 + 1][d4 * 4]);
#pragma unroll
        for (int i = 0; i < 4; ++i) {
#pragma unroll
            for (int j = 0; j < 2; ++j) {
                acc[i][j] = fmaf(xv[i].x, wv[j].x, acc[i][j]);
                acc[i][j] = fmaf(xv[i].y, wv[j].y, acc[i][j]);
                acc[i][j] = fmaf(xv[i].z, wv[j].z, acc[i][j]);
                acc[i][j] = fmaf(xv[i].w, wv[j].w, acc[i][j]);
            }
        }
    }
#pragma unroll
    for (int j = 0; j < 2; ++j) {
        int g = g0 + gg * 2 + j;
        float bias = (g < 512) ? (bif[g] + bhf[g]) : (bib[g - 512] + bhb[g - 512]);
#pragma unroll
        for (int i = 0; i < 4; ++i) {
            int r = r0 + mg * 4 + i;
            int t = r >> 3, bb = r & 7;
            float v = acc[i][j] + bias;
            if (g < 512) {
                int p = 4 * (g & 127) + (g >> 7);
                xpf[((size_t)t * BB + bb) * 512 + p] = v;
            } else {
                int gb = g - 512;
                int p = 4 * (gb & 127) + (gb >> 7);
                xpb[((size_t)(NN - 1 - t) * BB + bb) * 512 + p] = v;
            }
        }
    }
}

// ---------------- Kernel 3: LSTM recurrence ----------------
// One block per (batch, dir), 512 threads. Quad q (threads 4q..4q+3) owns
// hidden UNIT q; lane jq holds, for all 4 gate types j, the partial dot of
// W_hh row (j*128+q) over h-cols [32*jq,32*jq+32). After 4 DPP quad-sums
// every lane has all 4 complete pre-activations -> redundant c/h update,
// no gate exchange, single barrier with double-buffered h.
// W pinned in VGPRs via empty asm (compiler would otherwise re-load from L2
// each step: R3 showed VGPR=96 + ~2000cyc/step of L2 traffic).
__global__ __attribute__((amdgpu_flat_work_group_size(512, 512), amdgpu_waves_per_eu(2, 2)))
void k_lstm(const float* __restrict__ xpf,
            const float* __restrict__ xpb,
            const float* __restrict__ whf,
            const float* __restrict__ whb,
            float* __restrict__ out) {
    const int b = blockIdx.x;
    const int dir = blockIdx.y;
    const float* __restrict__ xp = (dir ? xpb : xpf) + (size_t)b * 512;
    const float* __restrict__ wh = dir ? whb : whf;
    const int t = threadIdx.x;  // 0..511
    const int q = t >> 2;       // unit id 0..127
    const int jq = t & 3;       // h-column group / xp gate-type slot

    __shared__ __align__(16) float h_lds[2][HH];

    // Load W rows {j*128+q : j=0..3}, cols jq*32..+31, k-rotated by 2*jq so the
    // four distinct 16B LDS broadcast addresses per read land in distinct banks.
    f4 w4[4][8];
#pragma unroll
    for (int j = 0; j < 4; ++j)
#pragma unroll
        for (int k = 0; k < 8; ++k) {
            int col = jq * 32 + (((k + 2 * jq) & 7) << 2);
            w4[j][k] = *(const f4*)(wh + (size_t)(j * 128 + q) * HH + col);
        }
    // Pin W in VGPRs: values become asm outputs -> not rematerializable.
#pragma unroll
    for (int j = 0; j < 4; ++j)
#pragma unroll
        for (int k = 0; k < 8; ++k) asm volatile("" : "+v"(w4[j][k]));

    if (t < HH) h_lds[0][t] = 0.f;
    __syncthreads();

    float c = 0.f, h = 0.f;
    float xpv = xp[t];  // step 0, permuted layout: slot 4q+jq = (unit q, type jq)
    int cur = 0;

    for (int step = 0; step < NN; ++step) {
        int sn = step + 1 < NN ? step + 1 : NN - 1;
        float xpn = xp[(size_t)sn * BB * 512 + t];

        f4 h4[8];
#pragma unroll
        for (int k = 0; k < 8; ++k) {
            int col = jq * 32 + (((k + 2 * jq) & 7) << 2);
            h4[k] = *(const f4*)(&h_lds[cur][col]);
        }
        f4 acc0 = {0.f, 0.f, 0.f, 0.f}, acc1 = acc0, acc2 = acc0, acc3 = acc0;
#pragma unroll
        for (int k = 0; k < 8; ++k) {
            acc0 = __builtin_elementwise_fma(w4[0][k], h4[k], acc0);
            acc1 = __builtin_elementwise_fma(w4[1][k], h4[k], acc1);
            acc2 = __builtin_elementwise_fma(w4[2][k], h4[k], acc2);
            acc3 = __builtin_elementwise_fma(w4[3][k], h4[k], acc3);
        }
        float p0 = (acc0.x + acc0.y) + (acc0.z + acc0.w);
        float p1 = (acc1.x + acc1.y) + (acc1.z + acc1.w);
        float p2 = (acc2.x + acc2.y) + (acc2.z + acc2.w);
        float p3 = (acc3.x + acc3.y) + (acc3.z + acc3.w);
        // inject xp for gate (type jq, unit q) exactly once into the quad sum
        p0 += (jq == 0) ? xpv : 0.f;
        p1 += (jq == 1) ? xpv : 0.f;
        p2 += (jq == 2) ? xpv : 0.f;
        p3 += (jq == 3) ? xpv : 0.f;
        float gi_ = quad_sum(p0);
        float gf_ = quad_sum(p1);
        float gg_ = quad_sum(p2);
        float go_ = quad_sum(p3);
        // redundant (identical) update in all 4 lanes of the quad
        c = fmaf(sigmoidf_(gf_), c, sigmoidf_(gi_) * tanhf_(gg_));
        h = sigmoidf_(go_) * tanhf_(c);
        if (jq == 0) h_lds[cur ^ 1][q] = h;
        __syncthreads();
        cur ^= 1;
        xpv = xpn;
    }
    if (jq == 0) out[(size_t)b * 256 + dir * HH + q] = h;
}

extern "C" void kernel_launch(void* const* d_in, const int* in_sizes, int n_in,
                              void* d_out, int out_size, void* d_ws, size_t ws_size,
                              hipStream_t stream) {
    const float* x = (const float*)d_in[0];
    const int* adj = (const int*)d_in[1];
    const float* wif = (const float*)d_in[2];
    const float* whf = (const float*)d_in[3];
    const float* bif = (const float*)d_in[4];
    const float* bhf = (const float*)d_in[5];
    const float* wib = (const float*)d_in[6];
    const float* whb = (const float*)d_in[7];
    const float* bib = (const float*)d_in[8];
    const float* bhb = (const float*)d_in[9];
    float* out = (float*)d_out;

    float* xa = (float*)d_ws;                            // [B][N][D]
    float* xpf = xa + (size_t)BB * NN * DD;              // [N][B][512]
    float* xpb = xpf + (size_t)NN * BB * 512;            // [N][B][512]

    k_agg<<<dim3(NN / TI, BB), 256, 0, stream>>>(x, adj, xa);
    k_proj<<<dim3((NN * BB) / MT, 1024 / GT), 256, 0, stream>>>(xa, wif, wib, bif, bhf, bib, bhb,
                                                                xpf, xpb);
    k_lstm<<<dim3(BB, 2), 512, 0, stream>>>(xpf, xpb, whf, whb, out);
}

// Round 5
// 1669.351 us; speedup vs baseline: 1.0337x; 1.0337x over previous
//
#include <hip/hip_runtime.h>
#include <math.h>

#define BB 8
#define NN 2048
#define DD 128
#define HH 128

typedef float f4 __attribute__((ext_vector_type(4)));

// ---------- fast math helpers ----------
__device__ __forceinline__ float fast_rcp(float x) { return __builtin_amdgcn_rcpf(x); }
__device__ __forceinline__ float sigmoidf_(float x) {
    x = fminf(fmaxf(x, -30.f), 30.f);
    return fast_rcp(1.f + __expf(-x));
}
__device__ __forceinline__ float tanhf_(float x) {
    x = fminf(fmaxf(x, -15.f), 15.f);
    float e = __expf(-2.f * x);
    return (1.f - e) * fast_rcp(1.f + e);
}

// DPP quad reduction: sum across the 4 lanes of each aligned quad (pure VALU).
__device__ __forceinline__ float quad_sum(float v) {
    int a = __builtin_amdgcn_update_dpp(0, __float_as_int(v), 0xB1, 0xF, 0xF, true);  // xor 1
    v += __int_as_float(a);
    int b = __builtin_amdgcn_update_dpp(0, __float_as_int(v), 0x4E, 0xF, 0xF, true);  // xor 2
    v += __int_as_float(b);
    return v;
}

// ---------------- Kernel 1: graph aggregation ----------------
#define TI 32
#define TJ 64

__global__ __launch_bounds__(256) void k_agg(const float* __restrict__ x,
                                             const int* __restrict__ adj,
                                             float* __restrict__ xa) {
    __shared__ __align__(16) float xs[TJ][132];
    __shared__ __align__(16) float as[TI][68];
    const int b = blockIdx.y;
    const int i0 = blockIdx.x * TI;
    const int tid = threadIdx.x;
    const int ig = tid >> 5;
    const int dg = tid & 31;
    const float* xb = x + (size_t)b * NN * DD;
    const int* ab = adj + (size_t)b * NN * NN;

    float acc[4][4];
    float deg[4];
#pragma unroll
    for (int i = 0; i < 4; ++i) {
        deg[i] = 0.f;
#pragma unroll
        for (int d = 0; d < 4; ++d) acc[i][d] = 0.f;
    }

    for (int j0 = 0; j0 < NN; j0 += TJ) {
#pragma unroll
        for (int k = 0; k < 8; ++k) {
            int idx = tid + k * 256;
            int row = idx >> 5, c4 = idx & 31;
            float4 v = *(const float4*)(xb + (size_t)(j0 + row) * DD + c4 * 4);
            *(float4*)(&xs[row][c4 * 4]) = v;
        }
#pragma unroll
        for (int k = 0; k < 2; ++k) {
            int idx = tid + k * 256;
            int row = idx >> 4, c4 = idx & 15;
            int4 v = *(const int4*)(ab + (size_t)(i0 + row) * NN + j0 + c4 * 4);
            float4 f;
            f.x = v.x > 0 ? 1.f : 0.f;
            f.y = v.y > 0 ? 1.f : 0.f;
            f.z = v.z > 0 ? 1.f : 0.f;
            f.w = v.w > 0 ? 1.f : 0.f;
            *(float4*)(&as[row][c4 * 4]) = f;
        }
        __syncthreads();
#pragma unroll 4
        for (int jq = 0; jq < TJ; jq += 4) {
            float4 av[4], xv[4];
#pragma unroll
            for (int i = 0; i < 4; ++i) av[i] = *(const float4*)(&as[ig * 4 + i][jq]);
#pragma unroll
            for (int jj = 0; jj < 4; ++jj) xv[jj] = *(const float4*)(&xs[jq + jj][dg * 4]);
#pragma unroll
            for (int i = 0; i < 4; ++i) {
                const float* ap = (const float*)&av[i];
#pragma unroll
                for (int jj = 0; jj < 4; ++jj) {
                    float a = ap[jj];
                    const float* xp4 = (const float*)&xv[jj];
                    deg[i] += a;
                    acc[i][0] = fmaf(a, xp4[0], acc[i][0]);
                    acc[i][1] = fmaf(a, xp4[1], acc[i][1]);
                    acc[i][2] = fmaf(a, xp4[2], acc[i][2]);
                    acc[i][3] = fmaf(a, xp4[3], acc[i][3]);
                }
            }
        }
        __syncthreads();
    }
#pragma unroll
    for (int i = 0; i < 4; ++i) {
        int gi = i0 + ig * 4 + i;
        float r = fast_rcp(1.f + deg[i]);
        float4 xv = *(const float4*)(xb + (size_t)gi * DD + dg * 4);
        float4 o;
        o.x = (xv.x + acc[i][0]) * r;
        o.y = (xv.y + acc[i][1]) * r;
        o.z = (xv.z + acc[i][2]) * r;
        o.w = (xv.w + acc[i][3]) * r;
        *(float4*)(xa + ((size_t)b * NN + gi) * DD + dg * 4) = o;
    }
}

// ---------------- Kernel 2: input projection (both dirs) ----------------
// Writes xp pre-permuted for k_lstm: gate (unit u, type j) -> slot 4*u+j.
// Backward dir also pre-reversed in time.
#define MT 64
#define GT 32

__global__ __launch_bounds__(256) void k_proj(const float* __restrict__ xa,
                                              const float* __restrict__ wif,
                                              const float* __restrict__ wib,
                                              const float* __restrict__ bif,
                                              const float* __restrict__ bhf,
                                              const float* __restrict__ bib,
                                              const float* __restrict__ bhb,
                                              float* __restrict__ xpf,
                                              float* __restrict__ xpb) {
    __shared__ __align__(16) float xs[MT][132];
    __shared__ __align__(16) float wl[GT][132];
    const int r0 = blockIdx.x * MT;
    const int g0 = blockIdx.y * GT;
    const int tid = threadIdx.x;
#pragma unroll
    for (int k = 0; k < 8; ++k) {
        int idx = tid + k * 256;
        int row = idx >> 5, c4 = idx & 31;
        int r = r0 + row;
        int t = r >> 3, bb = r & 7;
        float4 v = *(const float4*)(xa + ((size_t)bb * NN + t) * DD + c4 * 4);
        *(float4*)(&xs[row][c4 * 4]) = v;
    }
#pragma unroll
    for (int k = 0; k < 4; ++k) {
        int idx = tid + k * 256;
        int row = idx >> 5, c4 = idx & 31;
        int g = g0 + row;
        const float* wsrc = (g < 512) ? (wif + (size_t)g * DD) : (wib + (size_t)(g - 512) * DD);
        *(float4*)(&wl[row][c4 * 4]) = *(const float4*)(wsrc + c4 * 4);
    }
    __syncthreads();
    const int mg = tid >> 4;
    const int gg = tid & 15;
    float acc[4][2];
#pragma unroll
    for (int i = 0; i < 4; ++i) { acc[i][0] = 0.f; acc[i][1] = 0.f; }
#pragma unroll 8
    for (int d4 = 0; d4 < 32; ++d4) {
        float4 xv[4], wv[2];
#pragma unroll
        for (int i = 0; i < 4; ++i) xv[i] = *(const float4*)(&xs[mg * 4 + i][d4 * 4]);
        wv[0] = *(const float4*)(&wl[gg * 2 + 0][d4 * 4]);
        wv[1] = *(const float4*)(&wl[gg * 2 + 1][d4 * 4]);
#pragma unroll
        for (int i = 0; i < 4; ++i) {
#pragma unroll
            for (int j = 0; j < 2; ++j) {
                acc[i][j] = fmaf(xv[i].x, wv[j].x, acc[i][j]);
                acc[i][j] = fmaf(xv[i].y, wv[j].y, acc[i][j]);
                acc[i][j] = fmaf(xv[i].z, wv[j].z, acc[i][j]);
                acc[i][j] = fmaf(xv[i].w, wv[j].w, acc[i][j]);
            }
        }
    }
#pragma unroll
    for (int j = 0; j < 2; ++j) {
        int g = g0 + gg * 2 + j;
        float bias = (g < 512) ? (bif[g] + bhf[g]) : (bib[g - 512] + bhb[g - 512]);
#pragma unroll
        for (int i = 0; i < 4; ++i) {
            int r = r0 + mg * 4 + i;
            int t = r >> 3, bb = r & 7;
            float v = acc[i][j] + bias;
            if (g < 512) {
                int p = 4 * (g & 127) + (g >> 7);
                xpf[((size_t)t * BB + bb) * 512 + p] = v;
            } else {
                int gb = g - 512;
                int p = 4 * (gb & 127) + (gb >> 7);
                xpb[((size_t)(NN - 1 - t) * BB + bb) * 512 + p] = v;
            }
        }
    }
}

// Pin 16 f4 values into arch VGPRs at this program point (emits no code when
// they are already resident; forbids AGPR/scratch homing across the use).
#define PIN16(A)                                                                     \
    asm volatile(""                                                                  \
                 : "+v"(A[0]), "+v"(A[1]), "+v"(A[2]), "+v"(A[3]), "+v"(A[4]),       \
                   "+v"(A[5]), "+v"(A[6]), "+v"(A[7]), "+v"(A[8]), "+v"(A[9]),       \
                   "+v"(A[10]), "+v"(A[11]), "+v"(A[12]), "+v"(A[13]), "+v"(A[14]),  \
                   "+v"(A[15]))

// ---------------- Kernel 3: LSTM recurrence ----------------
// One block per (batch, dir), 512 threads. Quad q (threads 4q..4q+3) owns
// hidden UNIT q; lane jq holds, for all 4 gate types j, the partial dot of
// W_hh row (j*128+q) over h-cols [32*jq,32*jq+32). After 4 DPP quad-sums
// every lane has all 4 complete pre-activations -> redundant c/h update,
// no gate exchange, single barrier with double-buffered h.
// R4 lesson: a pre-loop asm pin let the RA home W in AGPRs and copy back
// every step (VALUBusy up, no perf). The pin must execute EVERY iteration:
// then an AGPR home costs 128 copies/step and the RA keeps W in arch VGPRs.
__global__ __attribute__((amdgpu_flat_work_group_size(512, 512), amdgpu_waves_per_eu(2, 2)))
void k_lstm(const float* __restrict__ xpf,
            const float* __restrict__ xpb,
            const float* __restrict__ whf,
            const float* __restrict__ whb,
            float* __restrict__ out) {
    const int b = blockIdx.x;
    const int dir = blockIdx.y;
    const float* __restrict__ xp = (dir ? xpb : xpf) + (size_t)b * 512;
    const float* __restrict__ wh = dir ? whb : whf;
    const int t = threadIdx.x;  // 0..511
    const int q = t >> 2;       // unit id 0..127
    const int jq = t & 3;       // h-column group / xp gate-type slot

    __shared__ __align__(16) float h_lds[2][HH];

    // W rows {j*128+q : j=0..3}, cols jq*32..+31, k-rotated by 2*jq so the
    // four distinct 16B LDS broadcast addresses per read land in distinct banks.
    f4 wA[16], wB[16];  // wA = gate types 0,1 ; wB = types 2,3
#pragma unroll
    for (int j = 0; j < 2; ++j)
#pragma unroll
        for (int k = 0; k < 8; ++k) {
            int col = jq * 32 + (((k + 2 * jq) & 7) << 2);
            wA[j * 8 + k] = *(const f4*)(wh + (size_t)(j * 128 + q) * HH + col);
            wB[j * 8 + k] = *(const f4*)(wh + (size_t)((j + 2) * 128 + q) * HH + col);
        }

    // xp-injection selectors (exactly one lane of the quad injects each type;
    // fma(1.0,x,p) == p+x bit-exactly)
    const float s0 = (jq == 0) ? 1.f : 0.f;
    const float s1 = (jq == 1) ? 1.f : 0.f;
    const float s2 = (jq == 2) ? 1.f : 0.f;
    const float s3 = (jq == 3) ? 1.f : 0.f;

    if (t < HH) h_lds[0][t] = 0.f;
    __syncthreads();

    float c = 0.f, h = 0.f;
    float xpv = xp[t];  // step 0, permuted layout: slot 4q+jq = (unit q, type jq)
    int cur = 0;

    for (int step = 0; step < NN; ++step) {
        int sn = step + 1 < NN ? step + 1 : NN - 1;
        float xpn = xp[(size_t)sn * BB * 512 + t];

        // Force W to be arch-VGPR-resident at every iteration.
        PIN16(wA);
        PIN16(wB);

        f4 h4[8];
#pragma unroll
        for (int k = 0; k < 8; ++k) {
            int col = jq * 32 + (((k + 2 * jq) & 7) << 2);
            h4[k] = *(const f4*)(&h_lds[cur][col]);
        }
        f4 acc0 = {0.f, 0.f, 0.f, 0.f}, acc1 = acc0, acc2 = acc0, acc3 = acc0;
#pragma unroll
        for (int k = 0; k < 8; ++k) {
            acc0 = __builtin_elementwise_fma(wA[k], h4[k], acc0);
            acc1 = __builtin_elementwise_fma(wA[8 + k], h4[k], acc1);
            acc2 = __builtin_elementwise_fma(wB[k], h4[k], acc2);
            acc3 = __builtin_elementwise_fma(wB[8 + k], h4[k], acc3);
        }
        float p0 = (acc0.x + acc0.y) + (acc0.z + acc0.w);
        float p1 = (acc1.x + acc1.y) + (acc1.z + acc1.w);
        float p2 = (acc2.x + acc2.y) + (acc2.z + acc2.w);
        float p3 = (acc3.x + acc3.y) + (acc3.z + acc3.w);
        // inject xp for gate (type jq, unit q) exactly once into the quad sum
        p0 = fmaf(s0, xpv, p0);
        p1 = fmaf(s1, xpv, p1);
        p2 = fmaf(s2, xpv, p2);
        p3 = fmaf(s3, xpv, p3);
        float gi_ = quad_sum(p0);
        float gf_ = quad_sum(p1);
        float gg_ = quad_sum(p2);
        float go_ = quad_sum(p3);
        // redundant (identical) update in all 4 lanes of the quad
        c = fmaf(sigmoidf_(gf_), c, sigmoidf_(gi_) * tanhf_(gg_));
        h = sigmoidf_(go_) * tanhf_(c);
        if (jq == 0) h_lds[cur ^ 1][q] = h;
        __syncthreads();
        cur ^= 1;
        xpv = xpn;
    }
    if (jq == 0) out[(size_t)b * 256 + dir * HH + q] = h;
}

extern "C" void kernel_launch(void* const* d_in, const int* in_sizes, int n_in,
                              void* d_out, int out_size, void* d_ws, size_t ws_size,
                              hipStream_t stream) {
    const float* x = (const float*)d_in[0];
    const int* adj = (const int*)d_in[1];
    const float* wif = (const float*)d_in[2];
    const float* whf = (const float*)d_in[3];
    const float* bif = (const float*)d_in[4];
    const float* bhf = (const float*)d_in[5];
    const float* wib = (const float*)d_in[6];
    const float* whb = (const float*)d_in[7];
    const float* bib = (const float*)d_in[8];
    const float* bhb = (const float*)d_in[9];
    float* out = (float*)d_out;

    float* xa = (float*)d_ws;                            // [B][N][D]
    float* xpf = xa + (size_t)BB * NN * DD;              // [N][B][512]
    float* xpb = xpf + (size_t)NN * BB * 512;            // [N][B][512]

    k_agg<<<dim3(NN / TI, BB), 256, 0, stream>>>(x, adj, xa);
    k_proj<<<dim3((NN * BB) / MT, 1024 / GT), 256, 0, stream>>>(xa, wif, wib, bif, bhf, bib, bhb,
                                                                xpf, xpb);
    k_lstm<<<dim3(BB, 2), 512, 0, stream>>>(xpf, xpb, whf, whb, out);
}